// Round 2
// baseline (71.965 us; speedup 1.0000x reference)
//
#include <hip/hip_runtime.h>

#define NB 32
#define TT 4096
#define DD 768
#define NJ 64
#define NK 64
#define NCLAUSES (NB * NJ)

// Persistent blocks; each grabs the next (doc, clause) from a global atomic
// queue (perfect load balance over ragged clause lengths). 4 waves per block;
// each wave processes rows k, k+4, ... Row dot-products vs fc_w and emo_w
// -> LDS; wave 0 does softmax + sigmoid.
__global__ __launch_bounds__(256) void clause_pool_kernel(
    const float* __restrict__ hs,         // [B, T, D]
    const int*   __restrict__ clause_len, // [B, J]
    const float* __restrict__ fc_w,       // [D]
    const float* __restrict__ fc_b,       // [1]
    const float* __restrict__ emo_w,      // [D]
    const float* __restrict__ emo_b,      // [1]
    float*       __restrict__ out,        // [B, J]
    int*         __restrict__ queue)      // [1] work counter (zeroed on stream)
{
    const int tid  = threadIdx.x;
    const int lane = tid & 63;
    const int wave = tid >> 6;

    // Weight fragments: lane owns float4 chunks {lane, lane+64, lane+128}
    const float4* fw4 = (const float4*)fc_w;
    const float4* ew4 = (const float4*)emo_w;
    const float4 wf0 = fw4[lane], wf1 = fw4[lane + 64], wf2 = fw4[lane + 128];
    const float4 we0 = ew4[lane], we1 = ew4[lane + 64], we2 = ew4[lane + 128];
    const float fcb = fc_b[0];
    const float emb = emo_b[0];

    __shared__ float sfc[NK];
    __shared__ float sem[NK];
    __shared__ int   s_pos;

    for (;;) {
        if (tid == 0) s_pos = atomicAdd(queue, 1);
        __syncthreads();
        const int bj = s_pos;
        if (bj >= NCLAUSES) return;
        const int b = bj >> 6;
        const int j = bj & 63;

        // Clause start = exclusive prefix sum of clause_len[b, :j] (L2-resident).
        const int cl   = clause_len[(b << 6) + lane];
        const int clen = __shfl(cl, j, 64);
        int pre = (lane < j) ? cl : 0;
        #pragma unroll
        for (int s = 1; s < 64; s <<= 1) pre += __shfl_xor(pre, s, 64);
        const int start = pre;

        const float* base = hs + ((size_t)b * TT + (size_t)start) * DD;

        for (int k = wave; k < clen; k += 4) {
            const float4* row = (const float4*)(base + (size_t)k * DD);
            const float4 h0 = row[lane];
            const float4 h1 = row[lane + 64];
            const float4 h2 = row[lane + 128];

            float pf = h0.x * wf0.x;
            pf = fmaf(h0.y, wf0.y, pf); pf = fmaf(h0.z, wf0.z, pf); pf = fmaf(h0.w, wf0.w, pf);
            pf = fmaf(h1.x, wf1.x, pf); pf = fmaf(h1.y, wf1.y, pf);
            pf = fmaf(h1.z, wf1.z, pf); pf = fmaf(h1.w, wf1.w, pf);
            pf = fmaf(h2.x, wf2.x, pf); pf = fmaf(h2.y, wf2.y, pf);
            pf = fmaf(h2.z, wf2.z, pf); pf = fmaf(h2.w, wf2.w, pf);

            float pe = h0.x * we0.x;
            pe = fmaf(h0.y, we0.y, pe); pe = fmaf(h0.z, we0.z, pe); pe = fmaf(h0.w, we0.w, pe);
            pe = fmaf(h1.x, we1.x, pe); pe = fmaf(h1.y, we1.y, pe);
            pe = fmaf(h1.z, we1.z, pe); pe = fmaf(h1.w, we1.w, pe);
            pe = fmaf(h2.x, we2.x, pe); pe = fmaf(h2.y, we2.y, pe);
            pe = fmaf(h2.z, we2.z, pe); pe = fmaf(h2.w, we2.w, pe);

            #pragma unroll
            for (int s = 1; s < 64; s <<= 1) {
                pf += __shfl_xor(pf, s, 64);
                pe += __shfl_xor(pe, s, 64);
            }
            if (lane == 0) { sfc[k] = pf; sem[k] = pe; }
        }
        __syncthreads();

        if (wave == 0) {
            const bool valid = lane < clen;
            float v = valid ? (sfc[lane] + fcb) : -3.0e38f;
            float m = v;
            #pragma unroll
            for (int s = 1; s < 64; s <<= 1) m = fmaxf(m, __shfl_xor(m, s, 64));
            const float e  = valid ? __expf(v - m) : 0.0f;
            const float ws = valid ? (e * sem[lane]) : 0.0f;
            float Z = e, S = ws;
            #pragma unroll
            for (int s = 1; s < 64; s <<= 1) {
                Z += __shfl_xor(Z, s, 64);
                S += __shfl_xor(S, s, 64);
            }
            if (lane == 0) {
                const float logit = S / Z + emb;
                out[bj] = 1.0f / (1.0f + __expf(-logit));
            }
        }
        __syncthreads();  // protect sfc/sem/s_pos before next iteration
    }
}

extern "C" void kernel_launch(void* const* d_in, const int* in_sizes, int n_in,
                              void* d_out, int out_size, void* d_ws, size_t ws_size,
                              hipStream_t stream) {
    const float* hs         = (const float*)d_in[0];
    const int*   clause_len = (const int*)d_in[1];
    const float* fc_w       = (const float*)d_in[2];
    const float* fc_b       = (const float*)d_in[3];
    const float* emo_w      = (const float*)d_in[4];
    const float* emo_b      = (const float*)d_in[5];
    float* out = (float*)d_out;
    int* queue = (int*)d_ws;

    hipMemsetAsync(queue, 0, sizeof(int), stream);
    clause_pool_kernel<<<NCLAUSES, 256, 0, stream>>>(
        hs, clause_len, fc_w, fc_b, emo_w, emo_b, out, queue);
}

// Round 3
// 40.172 us; speedup vs baseline: 1.7914x; 1.7914x over previous
//
#include <hip/hip_runtime.h>

#define NB 32
#define TT 4096
#define DD 768
#define NJ 64
#define NK 64
#define NCLAUSES (NB * NJ)

#define ROWS_PER_CHUNK 32
#define CHUNKS_PER_DOC (TT / ROWS_PER_CHUNK)   // 128

// ---------------- Phase 1: per-token dual dot-products --------------------
// Block = 256 thr (4 waves). Block covers 32 consecutive token rows of one
// doc; wave w handles rows base + 4*i + w, i = 0..7. Only rows t < L_b
// (the used prefix) are processed. No LDS, no __syncthreads.
__global__ __launch_bounds__(256) void dots_kernel(
    const float* __restrict__ hs,         // [B, T, D]
    const int*   __restrict__ clause_len, // [B, J]
    const float* __restrict__ fc_w,       // [D]
    const float* __restrict__ emo_w,      // [D]
    float*       __restrict__ ws_fc,      // [B, T]
    float*       __restrict__ ws_emo)     // [B, T]
{
    const int b     = blockIdx.x >> 7;          // / CHUNKS_PER_DOC
    const int chunk = blockIdx.x & (CHUNKS_PER_DOC - 1);
    const int lane  = threadIdx.x & 63;
    const int wave  = threadIdx.x >> 6;

    // L_b = total used tokens in doc b (each wave computes redundantly; L2 hits)
    int L = clause_len[(b << 6) + lane];
    #pragma unroll
    for (int s = 1; s < 64; s <<= 1) L += __shfl_xor(L, s, 64);

    const int base = chunk * ROWS_PER_CHUNK;
    if (base + wave >= L) return;               // whole chunk-slice unused

    const float4* fw4 = (const float4*)fc_w;
    const float4* ew4 = (const float4*)emo_w;
    const float4 wf0 = fw4[lane], wf1 = fw4[lane + 64], wf2 = fw4[lane + 128];
    const float4 we0 = ew4[lane], we1 = ew4[lane + 64], we2 = ew4[lane + 128];

    for (int i = 0; i < 8; ++i) {
        const int t = base + (i << 2) + wave;
        if (t >= L) break;

        const float4* row = (const float4*)(hs + ((size_t)b * TT + t) * DD);
        const float4 h0 = row[lane];
        const float4 h1 = row[lane + 64];
        const float4 h2 = row[lane + 128];

        float pf = h0.x * wf0.x;
        pf = fmaf(h0.y, wf0.y, pf); pf = fmaf(h0.z, wf0.z, pf); pf = fmaf(h0.w, wf0.w, pf);
        pf = fmaf(h1.x, wf1.x, pf); pf = fmaf(h1.y, wf1.y, pf);
        pf = fmaf(h1.z, wf1.z, pf); pf = fmaf(h1.w, wf1.w, pf);
        pf = fmaf(h2.x, wf2.x, pf); pf = fmaf(h2.y, wf2.y, pf);
        pf = fmaf(h2.z, wf2.z, pf); pf = fmaf(h2.w, wf2.w, pf);

        float pe = h0.x * we0.x;
        pe = fmaf(h0.y, we0.y, pe); pe = fmaf(h0.z, we0.z, pe); pe = fmaf(h0.w, we0.w, pe);
        pe = fmaf(h1.x, we1.x, pe); pe = fmaf(h1.y, we1.y, pe);
        pe = fmaf(h1.z, we1.z, pe); pe = fmaf(h1.w, we1.w, pe);
        pe = fmaf(h2.x, we2.x, pe); pe = fmaf(h2.y, we2.y, pe);
        pe = fmaf(h2.z, we2.z, pe); pe = fmaf(h2.w, we2.w, pe);

        #pragma unroll
        for (int s = 1; s < 64; s <<= 1) {
            pf += __shfl_xor(pf, s, 64);
            pe += __shfl_xor(pe, s, 64);
        }
        if (lane == 0) {
            ws_fc [b * TT + t] = pf;
            ws_emo[b * TT + t] = pe;
        }
    }
}

// ---------------- Phase 2: per-clause softmax + sigmoid -------------------
// One wave per clause; 4 clauses per 256-thr block. Reads the per-token
// scalars from ws (L2/L3-resident).
__global__ __launch_bounds__(256) void pool_kernel(
    const int*   __restrict__ clause_len, // [B, J]
    const float* __restrict__ ws_fc,      // [B, T]
    const float* __restrict__ ws_emo,     // [B, T]
    const float* __restrict__ fc_b,       // [1]
    const float* __restrict__ emo_b,      // [1]
    float*       __restrict__ out)        // [B, J]
{
    const int lane = threadIdx.x & 63;
    const int wave = threadIdx.x >> 6;
    const int bj   = (blockIdx.x << 2) + wave;
    const int b    = bj >> 6;
    const int j    = bj & 63;

    const int cl   = clause_len[(b << 6) + lane];
    const int clen = __shfl(cl, j, 64);
    int pre = (lane < j) ? cl : 0;
    #pragma unroll
    for (int s = 1; s < 64; s <<= 1) pre += __shfl_xor(pre, s, 64);
    const int start = pre;

    const bool valid = lane < clen;
    const int  t     = start + lane;
    const float sfc  = valid ? ws_fc [b * TT + t] : 0.0f;
    const float sem  = valid ? ws_emo[b * TT + t] : 0.0f;

    float v = valid ? (sfc + fc_b[0]) : -3.0e38f;
    float m = v;
    #pragma unroll
    for (int s = 1; s < 64; s <<= 1) m = fmaxf(m, __shfl_xor(m, s, 64));
    const float e  = valid ? __expf(v - m) : 0.0f;
    const float wsum = e * sem;
    float Z = e, S = wsum;
    #pragma unroll
    for (int s = 1; s < 64; s <<= 1) {
        Z += __shfl_xor(Z, s, 64);
        S += __shfl_xor(S, s, 64);
    }
    if (lane == 0) {
        const float logit = S / Z + emo_b[0];
        out[bj] = 1.0f / (1.0f + __expf(-logit));
    }
}

extern "C" void kernel_launch(void* const* d_in, const int* in_sizes, int n_in,
                              void* d_out, int out_size, void* d_ws, size_t ws_size,
                              hipStream_t stream) {
    const float* hs         = (const float*)d_in[0];
    const int*   clause_len = (const int*)d_in[1];
    const float* fc_w       = (const float*)d_in[2];
    const float* fc_b       = (const float*)d_in[3];
    const float* emo_w      = (const float*)d_in[4];
    const float* emo_b      = (const float*)d_in[5];
    float* out = (float*)d_out;

    float* ws_fc  = (float*)d_ws;            // [B*T]
    float* ws_emo = ws_fc + NB * TT;         // [B*T]

    dots_kernel<<<NB * CHUNKS_PER_DOC, 256, 0, stream>>>(
        hs, clause_len, fc_w, emo_w, ws_fc, ws_emo);
    pool_kernel<<<NCLAUSES / 4, 256, 0, stream>>>(
        clause_len, ws_fc, ws_emo, fc_b, emo_b, out);
}